// Round 8
// baseline (44.392 us; speedup 1.0000x reference)
//
#include <hip/hip_runtime.h>

// Covariance from (scales, quaternion) — 3D Gaussian splatting head.
// out[n] = upper-tri(R diag(s^2) R^T) with R from normalized quat.
// Memory-bound. 4 rows/thread; wave-local LDS transpose so nt stores are
// lane-contiguous (R3/R4). Persistent grid (2048 blocks) + software
// pipeline — next chunk's global loads issue BEFORE the lgkm-only fence,
// so they fill under the store phase (vmcnt stays in flight across it).
// R8 fix: chunk output stride is 768 f32x4 (512 rows * 6 f32 / 4), was 384.

typedef float f32x4 __attribute__((ext_vector_type(4)));

__device__ __forceinline__ void cov6(float r, float x, float y, float z,
                                     float s0, float s1, float s2,
                                     float* __restrict__ o) {
    float inv = rsqrtf(r * r + x * x + y * y + z * z);
    r *= inv; x *= inv; y *= inv; z *= inv;
    float R00 = 1.f - 2.f * (y * y + z * z);
    float R01 = 2.f * (x * y - r * z);
    float R02 = 2.f * (x * z + r * y);
    float R10 = 2.f * (x * y + r * z);
    float R11 = 1.f - 2.f * (x * x + z * z);
    float R12 = 2.f * (y * z - r * x);
    float R20 = 2.f * (x * z - r * y);
    float R21 = 2.f * (y * z + r * x);
    float R22 = 1.f - 2.f * (x * x + y * y);
    float a = s0 * s0, b = s1 * s1, c = s2 * s2;
    o[0] = R00 * R00 * a + R01 * R01 * b + R02 * R02 * c;  // cov00
    o[1] = R00 * R10 * a + R01 * R11 * b + R02 * R12 * c;  // cov01
    o[2] = R00 * R20 * a + R01 * R21 * b + R02 * R22 * c;  // cov02
    o[3] = R10 * R10 * a + R11 * R11 * b + R12 * R12 * c;  // cov11
    o[4] = R10 * R20 * a + R11 * R21 * b + R12 * R22 * c;  // cov12
    o[5] = R20 * R20 * a + R21 * R21 * b + R22 * R22 * c;  // cov22
}

// XOR swizzle on f32x4 index: flips bit0 iff bit3. Involution, region-local.
// Measured 0 bank conflicts for both phases (R4).
__device__ __forceinline__ int swz(int g) { return g ^ ((g >> 3) & 1); }

__global__ __launch_bounds__(128) void gaus_cov_pipe(
    const float* __restrict__ scales,  // (N,3)
    const float* __restrict__ rots,    // (N,4)
    float* __restrict__ out,           // (N,6)
    int n, int nfull) {                // nfull = n/512 full chunks
    __shared__ f32x4 lds[768];         // 12 KB: 2 waves x 384 f32x4 slices
    const int t = threadIdx.x;
    const int w = t >> 6;              // wave id in block
    const int l = t & 63;              // lane id

    // Partial tail chunk (n % 512 != 0): block 0 handles it, scalar path.
    if (blockIdx.x == 0) {
        for (long long r = 512ll * nfull + t; r < n; r += 128) {
            float a0 = scales[3 * r + 0], a1 = scales[3 * r + 1], a2 = scales[3 * r + 2];
            const float4* rp = reinterpret_cast<const float4*>(rots + 4 * r);
            float4 q = rp[0];
            float o[6];
            cov6(q.x, q.y, q.z, q.w, a0, a1, a2, o);
            float* op = out + 6 * r;
            op[0] = o[0]; op[1] = o[1]; op[2] = o[2];
            op[3] = o[3]; op[4] = o[4]; op[5] = o[5];
        }
    }

    int cid = blockIdx.x;
    if (cid >= nfull) return;

    // Prologue: load chunk `cid`.
    float4 s0, s1, s2, q0, q1, q2, q3;
    {
        const long long gt = 128ll * cid + t;            // global quad index
        const float4* sp = reinterpret_cast<const float4*>(scales + 12ll * gt);
        s0 = sp[0]; s1 = sp[1]; s2 = sp[2];
        const float4* rp = reinterpret_cast<const float4*>(rots + 16ll * gt);
        q0 = rp[0]; q1 = rp[1]; q2 = rp[2]; q3 = rp[3];
    }

    while (true) {
        const int nxt = cid + (int)gridDim.x;
        const bool have_next = nxt < nfull;

        // Compute current chunk (4 rows/thread).
        float o[24];
        cov6(q0.x, q0.y, q0.z, q0.w, s0.x, s0.y, s0.z, o);
        cov6(q1.x, q1.y, q1.z, q1.w, s0.w, s1.x, s1.y, o + 6);
        cov6(q2.x, q2.y, q2.z, q2.w, s1.z, s1.w, s2.x, o + 12);
        cov6(q3.x, q3.y, q3.z, q3.w, s2.y, s2.z, s2.w, o + 18);

        // Issue next chunk's loads NOW — they fill under the store phase.
        if (have_next) {
            const long long gt = 128ll * nxt + t;
            const float4* sp = reinterpret_cast<const float4*>(scales + 12ll * gt);
            s0 = sp[0]; s1 = sp[1]; s2 = sp[2];
            const float4* rp = reinterpret_cast<const float4*>(rots + 16ll * gt);
            q0 = rp[0]; q1 = rp[1]; q2 = rp[2]; q3 = rp[3];
        }

        // Transpose through this wave's LDS slice [384w, 384w+384).
        #pragma unroll
        for (int j = 0; j < 6; ++j) {
            f32x4 v = {o[4 * j], o[4 * j + 1], o[4 * j + 2], o[4 * j + 3]};
            lds[swz(6 * t + j)] = v;
        }
        // Wave-local fence: drain DS only (lgkm) — global loads stay in
        // flight (vmcnt untouched). No block barrier.
        __builtin_amdgcn_wave_barrier();
        asm volatile("s_waitcnt lgkmcnt(0)" ::: "memory");
        __builtin_amdgcn_sched_barrier(0);
        // Coalesced nontemporal stores: lanes contiguous, 1KB per wave-instr.
        // Chunk stride = 768 f32x4 (512 rows * 6 floats / 4). (R8 fix)
        f32x4* op = reinterpret_cast<f32x4*>(out) + 768ll * cid;
        #pragma unroll
        for (int k = 0; k < 6; ++k) {
            int g = 384 * w + 64 * k + l;
            f32x4 v = lds[swz(g)];
            __builtin_nontemporal_store(v, op + g);
        }
        if (!have_next) break;
        cid = nxt;
    }
}

extern "C" void kernel_launch(void* const* d_in, const int* in_sizes, int n_in,
                              void* d_out, int out_size, void* d_ws, size_t ws_size,
                              hipStream_t stream) {
    const float* scales = (const float*)d_in[0];
    const float* rots   = (const float*)d_in[1];
    float* out = (float*)d_out;
    int n = in_sizes[0] / 3;           // N rows
    int nfull = (int)(n / 512ll);      // full 512-row chunks
    int grid = nfull < 2048 ? (nfull > 0 ? nfull : 1) : 2048;
    gaus_cov_pipe<<<grid, 128, 0, stream>>>(scales, rots, out, n, nfull);
}

// Round 9
// 42.675 us; speedup vs baseline: 1.0402x; 1.0402x over previous
//
#include <hip/hip_runtime.h>

// Covariance from (scales, quaternion) — 3D Gaussian splatting head.
// out[n] = upper-tri(R diag(s^2) R^T) with R from normalized quat.
// Memory/fabric-bound: logical traffic 266 MB (143 in + 123 out) at the
// ~6.3 TB/s L2-fabric ceiling -> 42.3 us floor. This variant measured
// 42.83 us (R4) = 98.8% of that floor. Output staged through LDS so
// nontemporal stores are lane-contiguous (4KB/wave-instr): no partial-line
// write amplification (R3 lesson: strided nt stores -> 2.9x WRITE_SIZE).
// Wave-local/persistent/pipelined variants (R5/R6/R8) all within noise or
// worse -> fabric-bound confirmed, structure doesn't matter past this point.

typedef float f32x4 __attribute__((ext_vector_type(4)));

__device__ __forceinline__ void cov6(float r, float x, float y, float z,
                                     float s0, float s1, float s2,
                                     float* __restrict__ o) {
    float inv = rsqrtf(r * r + x * x + y * y + z * z);
    r *= inv; x *= inv; y *= inv; z *= inv;
    float R00 = 1.f - 2.f * (y * y + z * z);
    float R01 = 2.f * (x * y - r * z);
    float R02 = 2.f * (x * z + r * y);
    float R10 = 2.f * (x * y + r * z);
    float R11 = 1.f - 2.f * (x * x + z * z);
    float R12 = 2.f * (y * z - r * x);
    float R20 = 2.f * (x * z - r * y);
    float R21 = 2.f * (y * z + r * x);
    float R22 = 1.f - 2.f * (x * x + y * y);
    float a = s0 * s0, b = s1 * s1, c = s2 * s2;
    o[0] = R00 * R00 * a + R01 * R01 * b + R02 * R02 * c;  // cov00
    o[1] = R00 * R10 * a + R01 * R11 * b + R02 * R12 * c;  // cov01
    o[2] = R00 * R20 * a + R01 * R21 * b + R02 * R22 * c;  // cov02
    o[3] = R10 * R10 * a + R11 * R11 * b + R12 * R12 * c;  // cov11
    o[4] = R10 * R20 * a + R11 * R21 * b + R12 * R22 * c;  // cov12
    o[5] = R20 * R20 * a + R21 * R21 * b + R22 * R22 * c;  // cov22
}

// XOR swizzle: flips bit0 of the float4 index iff bit3 is set. Involution.
// Write side (stride-6 float4 per lane) hits all 8 superbanks uniformly;
// read side (stride-1) stays uniform. Measured 0 bank conflicts (R4).
__device__ __forceinline__ int swz(int g) { return g ^ ((g >> 3) & 1); }

__global__ __launch_bounds__(256) void gaus_cov_lds(
    const float* __restrict__ scales,  // (N,3)
    const float* __restrict__ rots,    // (N,4)
    float* __restrict__ out,           // (N,6)
    int n) {
    __shared__ f32x4 lds[1536];        // 1024 rows * 6 f32 = 24 KB
    const int t = threadIdx.x;
    const long long blockRow = 1024ll * blockIdx.x;

    if (blockRow + 1024 <= n) {
        // Fast path: whole block in range. 4 rows/thread, all I/O float4.
        const long long gt = blockRow / 4 + t;           // global quad index
        const float4* sp = reinterpret_cast<const float4*>(scales + 12ll * gt);
        float4 s0 = sp[0], s1 = sp[1], s2 = sp[2];
        const float4* rp = reinterpret_cast<const float4*>(rots + 16ll * gt);
        float4 q0 = rp[0], q1 = rp[1], q2 = rp[2], q3 = rp[3];
        float o[24];
        cov6(q0.x, q0.y, q0.z, q0.w, s0.x, s0.y, s0.z, o);
        cov6(q1.x, q1.y, q1.z, q1.w, s0.w, s1.x, s1.y, o + 6);
        cov6(q2.x, q2.y, q2.z, q2.w, s1.z, s1.w, s2.x, o + 12);
        cov6(q3.x, q3.y, q3.z, q3.w, s2.y, s2.z, s2.w, o + 18);
        #pragma unroll
        for (int j = 0; j < 6; ++j) {
            f32x4 v = {o[4 * j], o[4 * j + 1], o[4 * j + 2], o[4 * j + 3]};
            lds[swz(6 * t + j)] = v;
        }
        __syncthreads();
        // Coalesced nontemporal stores: lanes contiguous, 4KB per wave-instr.
        f32x4* op = reinterpret_cast<f32x4*>(out) + 1536ll * blockIdx.x;
        #pragma unroll
        for (int k = 0; k < 6; ++k) {
            int g = t + 256 * k;
            f32x4 v = lds[swz(g)];
            __builtin_nontemporal_store(v, op + g);
        }
    } else {
        // Tail block (n % 1024 != 0): scalar per-row, plain stores.
        for (int rr = 0; rr < 4; ++rr) {
            long long r = blockRow + 4ll * t + rr;
            if (r >= n) break;
            float a0 = scales[3ll * r + 0];
            float a1 = scales[3ll * r + 1];
            float a2 = scales[3ll * r + 2];
            const float4* rp = reinterpret_cast<const float4*>(rots + 4ll * r);
            float4 q = rp[0];
            float o[6];
            cov6(q.x, q.y, q.z, q.w, a0, a1, a2, o);
            float* op = out + 6ll * r;
            op[0] = o[0]; op[1] = o[1]; op[2] = o[2];
            op[3] = o[3]; op[4] = o[4]; op[5] = o[5];
        }
    }
}

extern "C" void kernel_launch(void* const* d_in, const int* in_sizes, int n_in,
                              void* d_out, int out_size, void* d_ws, size_t ws_size,
                              hipStream_t stream) {
    const float* scales = (const float*)d_in[0];
    const float* rots   = (const float*)d_in[1];
    float* out = (float*)d_out;
    int n = in_sizes[0] / 3;           // N rows
    int nblocks = (int)((n + 1023ll) / 1024ll);
    gaus_cov_lds<<<nblocks, 256, 0, stream>>>(scales, rots, out, n);
}